// Round 8
// baseline (131.416 us; speedup 1.0000x reference)
//
#include <hip/hip_runtime.h>
#include <math.h>

#define HW 4096      // 64*64 feature locations
#define CC 256       // feature channels
#define C2 64        // value channels
#define E50f 1.928749848e-22f   // expf(-50)

typedef unsigned short USH;
typedef __attribute__((ext_vector_type(8))) _Float16 f16x8;
typedef __attribute__((ext_vector_type(8))) short bf8;
typedef __attribute__((ext_vector_type(4))) float f32x4;

__device__ __forceinline__ USH f2bf(float x) {
    unsigned u = __float_as_uint(x);
    u += 0x7fff + ((u >> 16) & 1);   // round-to-nearest-even
    return (USH)(u >> 16);
}
__device__ __forceinline__ USH f2h(float x) {
    _Float16 h = (_Float16)x;        // v_cvt_f16_f32, RTNE
    return *(USH*)&h;
}

// async global->LDS DMA, 16B per lane; LDS base must be wave-uniform
__device__ __forceinline__ void gl2lds16(const USH* g, USH* l) {
    __builtin_amdgcn_global_load_lds(
        (const __attribute__((address_space(1))) void*)g,
        (__attribute__((address_space(3))) void*)l, 16, 0, 0);
}

// ---------------------------------------------------------------------------
// D1: merged prep. blocks [0,512): per-channel means of fa/fb.
//     blocks [512,1536): bilinear 256->64 of unalign_fb fused with mask_b,
//     vtT build (chunked [qc][256m][32] bf16) and per-(pblock) bg partials.
// bgp layout: [pblk][320]: [0..255] rowsum[m] partials, [256..319] tot[c2].
__global__ void k_prep1(const float* __restrict__ fa, const float* __restrict__ fb,
                        float* __restrict__ mu,
                        const float* __restrict__ ufb_src, const int* __restrict__ fb_parse,
                        USH* __restrict__ vtT, float* __restrict__ bgp) {
    __shared__ float4 sred[256];
    int t = threadIdx.x;
    if (blockIdx.x < 512) {
        int b = blockIdx.x;
        const float* src = (b < CC) ? (fa + b * HW) : (fb + (b - CC) * HW);
        float s = 0.f;
        for (int q = t; q < HW; q += 256) s += src[q];
        sred[t].x = s;
        __syncthreads();
        for (int st = 128; st > 0; st >>= 1) {
            if (t < st) sred[t].x += sred[t + st].x;
            __syncthreads();
        }
        if (t == 0) mu[b] = sred[0].x * (1.0f / HW);
        return;
    }
    int bid = blockIdx.x - 512;
    int pblk = bid & 15, c = bid >> 4;
    int p = pblk * 256 + t;
    int j = p >> 6, i = p & 63;
    int off = (4 * j) * 256 + 4 * i;   // nearest: src = 4*dst
    float m0 = (fb_parse[1 * 65536 + off] != 0) ? 1.f : 0.f;
    float m1 = (fb_parse[2 * 65536 + off] != 0) ? 1.f : 0.f;
    float m2 = (fb_parse[3 * 65536 + off] != 0) ? 1.f : 0.f;
    float ry = j * (255.0f / 63.0f);
    int y0 = (int)ry; y0 = min(y0, 255); int y1 = min(y0 + 1, 255);
    float wy = ry - (float)y0;
    float rx = i * (255.0f / 63.0f);
    int x0 = (int)rx; x0 = min(x0, 255); int x1 = min(x0 + 1, 255);
    float wx = rx - (float)x0;
    const float* sc = ufb_src + c * 65536;
    float r0 = sc[y0 * 256 + x0] * (1.f - wx) + sc[y0 * 256 + x1] * wx;
    float r1 = sc[y1 * 256 + x0] * (1.f - wx) + sc[y1 * 256 + x1] * wx;
    float v = r0 * (1.f - wy) + r1 * wy;
    size_t cbase = (size_t)(p >> 5) * 8192 + (p & 31);
    vtT[cbase + (0 * 65 + c) * 32] = f2bf(v * m0);
    vtT[cbase + (1 * 65 + c) * 32] = f2bf(v * m1);
    vtT[cbase + (2 * 65 + c) * 32] = f2bf(v * m2);
    if (c == 0) {
        vtT[cbase + 64 * 32]  = f2bf(m0);
        vtT[cbase + 129 * 32] = f2bf(m1);
        vtT[cbase + 194 * 32] = f2bf(m2);
        for (int m = 195; m < 256; ++m) vtT[cbase + m * 32] = 0;
    }
    sred[t] = make_float4(v, v * m0, v * m1, v * m2);
    __syncthreads();
    for (int st = 128; st > 0; st >>= 1) {
        if (t < st) {
            float4 o = sred[t + st];
            sred[t].x += o.x; sred[t].y += o.y; sred[t].z += o.z; sred[t].w += o.w;
        }
        __syncthreads();
    }
    if (t == 0) {
        float4 r = sred[0];
        bgp[pblk * 320 + 256 + c]     = r.x;   // tot[c]
        bgp[pblk * 320 + 0 * 65 + c]  = r.y;   // rowsum value rows
        bgp[pblk * 320 + 1 * 65 + c]  = r.z;
        bgp[pblk * 320 + 2 * 65 + c]  = r.w;
    }
    __syncthreads();
    if (c == 0) {   // mask-row sums (block-uniform branch)
        sred[t] = make_float4(m0, m1, m2, 0.f);
        __syncthreads();
        for (int st = 128; st > 0; st >>= 1) {
            if (t < st) {
                float4 o = sred[t + st];
                sred[t].x += o.x; sred[t].y += o.y; sred[t].z += o.z;
            }
            __syncthreads();
        }
        if (t == 0) {
            float4 r = sred[0];
            bgp[pblk * 320 + 64]  = r.x;
            bgp[pblk * 320 + 129] = r.y;
            bgp[pblk * 320 + 194] = r.z;
        }
    }
}

// D2: fused center + L2-normalize + fp16 cast + chunked transpose.
// ssq summation order matches the original two-kernel path -> bit-identical.
__global__ __launch_bounds__(256) void k_normT(
    const float* __restrict__ fa, const float* __restrict__ fb,
    const float* __restrict__ mu_,
    USH* __restrict__ faT, USH* __restrict__ fbT) {
    __shared__ float tile[256][33];   // [c][p], +1 pad
    __shared__ float red[8][32];
    __shared__ float rv[32];
    int which = blockIdx.z;
    const float* src = which ? fb : fa;
    USH* dst = which ? fbT : faT;
    const float* mu = mu_ + which * CC;
    int p0 = blockIdx.x * 32;
    int t = threadIdx.x;
    int pi = t & 31, g = t >> 5;      // g in 0..7: 32-channel chunk
    for (int it = 0; it < 32; ++it) {
        int c = it * 8 + g;
        tile[c][pi] = src[(size_t)c * HW + p0 + pi];
    }
    __syncthreads();
    float ss = 0.f;
#pragma unroll
    for (int jc = 0; jc < 32; ++jc) {
        float v = tile[g * 32 + jc][pi] - mu[g * 32 + jc];
        ss += v * v;
    }
    red[g][pi] = ss;
    __syncthreads();
    if (g == 0) {
        float s2 = 0.f;
#pragma unroll
        for (int gg = 0; gg < 8; ++gg) s2 += red[gg][pi];
        rv[pi] = rsqrtf(s2);
    }
    __syncthreads();
    float rinv = rv[pi];
    size_t base = (size_t)g * 131072 + (size_t)(p0 + pi) * 32;
#pragma unroll
    for (int seg = 0; seg < 4; ++seg) {
        union { USH us[8]; uint4 v; } h;
#pragma unroll
        for (int jc = 0; jc < 8; ++jc)
            h.us[jc] = f2h((tile[g * 32 + seg * 8 + jc][pi] - mu[g * 32 + seg * 8 + jc]) * rinv);
        *(uint4*)&dst[base + seg * 8] = h.v;
    }
}

// D3: fused attention (v6, measured best). p-tile 128, 8 waves, 256 blocks
// (1/CU). XCD pinning z=bid&7; A staged once in LDS; B/V direct global->VGPR.
// Wave w: S-phase owns q rows 16w..16w+15; PV owns m rows 32w..32w+31.
__global__ __launch_bounds__(512, 2) void k_attn(
    const USH* __restrict__ faT, const USH* __restrict__ fbT,
    const USH* __restrict__ vtT, float* __restrict__ part) {
    __shared__ USH sA[8 * 4096];    // A tile [kc=8][128p][32c] fp16 (64 KB)
    __shared__ USH sE[128 * 136];   // E tile [128p][128q + pad] bf16 (34 KB)
    int t = threadIdx.x;
    int bid = blockIdx.x;
    int z = bid & 7;                // XCD = bid % 8 (round-robin)
    int p0 = (bid >> 3) * 128;
    int w = t >> 6, lane = t & 63, lr = lane & 15, quad = lane >> 4;
    f32x4 accp[2][8] = {};          // PV acc: m=32w+16i+4quad+r, p=p0+16jj+lr

    // prologue: stage the block's A-slice (128 rows x 256 ch) into LDS.
#pragma unroll
    for (int seg = 0; seg < 8; ++seg)
        gl2lds16(faT + (size_t)w * 131072 + (size_t)p0 * 32 + seg * 512 + lane * 8,
                 &sA[w * 4096 + seg * 512]);

    const USH* pB = fbT + (size_t)(z * 512 + 16 * w + lr) * 32 + quad * 8; // + kc*131072 + qt*4096
    const USH* pV = vtT + (size_t)(32 * w + lr) * 32 + quad * 8;           // + qc*8192 + i*512

    __syncthreads();               // A-stage complete (implies vmcnt drain)

    for (int qt = 0; qt < 4; ++qt) {
        f32x4 accs[8] = {};         // S acc: q=16w+4quad+r, p=16jj+lr
#pragma unroll
        for (int kc = 0; kc < 8; ++kc) {
            f16x8 a, b[8];
            a = *(const f16x8*)&pB[(size_t)kc * 131072 + qt * 4096];
#pragma unroll
            for (int jj = 0; jj < 8; ++jj)
                b[jj] = *(const f16x8*)&sA[kc * 4096 + (16 * jj + lr) * 32 + quad * 8];
#pragma unroll
            for (int jj = 0; jj < 8; ++jj)
                accs[jj] = __builtin_amdgcn_mfma_f32_16x16x32_f16(a, b[jj], accs[jj], 0, 0, 0);
        }
        // wait for previous qt's PV reads of sE before overwriting
        if (qt) __syncthreads();
        // exp -> bf16 -> transposed E tile in LDS: E[p][q]
#pragma unroll
        for (int jj = 0; jj < 8; ++jj) {
            unsigned u0 = ((unsigned)f2bf(__expf(fmaf(100.f, accs[jj][1], -50.f))) << 16)
                        | (unsigned)f2bf(__expf(fmaf(100.f, accs[jj][0], -50.f)));
            unsigned u1 = ((unsigned)f2bf(__expf(fmaf(100.f, accs[jj][3], -50.f))) << 16)
                        | (unsigned)f2bf(__expf(fmaf(100.f, accs[jj][2], -50.f)));
            int addr = (16 * jj + lr) * 136 + 16 * w + 4 * quad;
            uint2 u; u.x = u0; u.y = u1;
            *(uint2*)&sE[addr] = u;
        }
        __syncthreads();
        // PV: V from global (L2-hot), E from LDS.
        // pad rows m>=208: wave 7 all, wave 6 i==1 -> skip (wave-uniform).
#pragma unroll
        for (int kc = 0; kc < 4; ++kc) {
            size_t vb = (size_t)(z * 16 + qt * 4 + kc) * 8192;
            bf8 av[2] = {}, be[8];
#pragma unroll
            for (int i = 0; i < 2; ++i)
                if (!(w == 7 || (w == 6 && i == 1)))
                    av[i] = *(const bf8*)&pV[vb + i * 512];
#pragma unroll
            for (int jj = 0; jj < 8; ++jj)
                be[jj] = *(const bf8*)&sE[(16 * jj + lr) * 136 + kc * 32 + quad * 8];
#pragma unroll
            for (int i = 0; i < 2; ++i)
#pragma unroll
                for (int jj = 0; jj < 8; ++jj)
                    if (!(w == 7 || (w == 6 && i == 1)))
                        accp[i][jj] = __builtin_amdgcn_mfma_f32_16x16x32_bf16(av[i], be[jj], accp[i][jj], 0, 0, 0);
        }
    }
    // store only useful rows m < 195
    float* op = part + (size_t)z * 1048576;
#pragma unroll
    for (int i = 0; i < 2; ++i) {
        int m = 32 * w + 16 * i + 4 * quad;
#pragma unroll
        for (int jj = 0; jj < 8; ++jj) {
            int pc = p0 + 16 * jj + lr;
#pragma unroll
            for (int r = 0; r < 4; ++r)
                if (m + r < 195)
                    op[(size_t)(m + r) * HW + pc] = accp[i][jj][r];
        }
    }
}

// D4 (v8): fused combine + bilinear upsample. One block per (row-quarter, c2).
// Computes the <=18 aligned rows this out-quarter needs into LDS (per-element
// arithmetic chain copied verbatim from k_combine8 -> bit-identical), then
// upsamples 64x256 outputs from LDS. Kills the aligned global roundtrip and
// one kernel launch. den rows are L2-hot (384 KB unique, re-read per c2).
__global__ __launch_bounds__(256) void k_final(
    const float* __restrict__ part, const float* __restrict__ bgp,
    const int* __restrict__ fa_parse, float* __restrict__ out) {
    __shared__ float sal[18 * 64];
    __shared__ float sden[3];
    __shared__ float sc2v[4];   // [0..2] rowsum_k at c2, [3] tot[c2]
    int t = threadIdx.x;
    int c2 = blockIdx.y;
    int q = blockIdx.x;         // row-quarter of the 256-row output
    if (t < 7) {
        int idx = (t < 3) ? (t * 65 + 64) : ((t < 6) ? (t - 3) * 65 + c2 : 256 + c2);
        float s = 0.f;
#pragma unroll
        for (int pb = 0; pb < 16; ++pb) s += bgp[pb * 320 + idx];
        if (t < 3) sden[t] = s; else sc2v[t - 3] = s;
    }
    __syncthreads();
    int a0 = (64 * q * 63) / 255;            // first aligned row needed
    int nrows = min(18, 64 - a0);
    int nval = nrows * 64;
    for (int it = 0; it < 5; ++it) {
        int idx = it * 256 + t;
        if (idx < nval) {
            int p = (a0 + (idx >> 6)) * 64 + (idx & 63);
            int off = (4 * (p >> 6)) * 256 + 4 * (p & 63);
            float ma[3], den[3];
            float s = 0.f;
#pragma unroll
            for (int k = 0; k < 3; ++k) {
                ma[k] = (fa_parse[(k + 1) * 65536 + off] != 0) ? 1.f : 0.f;
                s += ma[k];
                den[k] = E50f * (4096.0f - sden[k]);
                size_t rd = (size_t)(k * 65 + 64) * HW + p;
#pragma unroll
                for (int z = 0; z < 8; ++z) den[k] += part[(size_t)z * 1048576 + rd];
            }
            float num = 0.f;
#pragma unroll
            for (int k = 0; k < 3; ++k) {
                float nu = E50f * (sc2v[3] - sc2v[k]);
                size_t rn = (size_t)(k * 65 + c2) * HW + p;
#pragma unroll
                for (int z = 0; z < 8; ++z) nu += part[(size_t)z * 1048576 + rn];
                num += ma[k] * (nu / den[k]);
            }
            sal[idx] = num / fmaxf(s, 1.f);
        }
    }
    __syncthreads();
    // upsample: out rows [64q, 64q+64), all 256 cols; 4 outputs per thread/iter
    float* op = out + (size_t)c2 * 65536 + (size_t)q * 64 * 256;
    for (int it = 0; it < 16; ++it) {
        int lin = (it * 256 + t) * 4;        // 0..16383 within the quarter
        int y = 64 * q + (lin >> 8);
        float ry = y * (63.0f / 255.0f);
        int y0 = (int)ry; y0 = min(y0, 63); int y1 = min(y0 + 1, 63);
        float wy = ry - (float)y0;
        const float* r0p = &sal[(y0 - a0) * 64];
        const float* r1p = &sal[(y1 - a0) * 64];
        float4 o;
        float* ov = &o.x;
#pragma unroll
        for (int u = 0; u < 4; ++u) {
            int x = (lin & 255) + u;
            float rx = x * (63.0f / 255.0f);
            int x0 = (int)rx; x0 = min(x0, 63); int x1 = min(x0 + 1, 63);
            float wx = rx - (float)x0;
            float r0 = r0p[x0] * (1.f - wx) + r0p[x1] * wx;
            float r1 = r1p[x0] * (1.f - wx) + r1p[x1] * wx;
            ov[u] = r0 * (1.f - wy) + r1 * wy;
        }
        *(float4*)&op[lin] = o;
    }
}

extern "C" void kernel_launch(void* const* d_in, const int* in_sizes, int n_in,
                              void* d_out, int out_size, void* d_ws, size_t ws_size,
                              hipStream_t stream) {
    const float* unalign_fb = (const float*)d_in[0];   // (1,64,256,256)
    const float* fa         = (const float*)d_in[1];   // (1,256,64,64)
    const int*   fa_parse   = (const int*)d_in[2];     // (1,4,256,256)
    const float* fb         = (const float*)d_in[3];   // (1,256,64,64)
    const int*   fb_parse   = (const int*)d_in[4];     // (1,4,256,256)
    float* out = (float*)d_out;                         // (1,64,256,256)

    float* w = (float*)d_ws;
    float* mu       = w;                   // 512
    float* bgp      = w + 66048;           // 16*320 = 5120
    float* part     = w + 71168;           // 8*1048576
    USH* faT = (USH*)(w + 8721920);        // [kc=8][4096p][32] fp16
    USH* fbT = (USH*)(w + 9246208);        // [kc=8][4096q][32] fp16
    USH* vtT = (USH*)(w + 9770496);        // [qc=128][256m][32] bf16

    k_prep1<<<dim3(1536), dim3(256), 0, stream>>>(fa, fb, mu, unalign_fb, fb_parse, vtT, bgp);
    k_normT<<<dim3(128, 1, 2), dim3(256), 0, stream>>>(fa, fb, mu, faT, fbT);
    k_attn<<<dim3(256), dim3(512), 0, stream>>>(faT, fbT, vtT, part);
    k_final<<<dim3(4, 64), dim3(256), 0, stream>>>(part, bgp, fa_parse, out);
}

// Round 9
// 129.052 us; speedup vs baseline: 1.0183x; 1.0183x over previous
//
#include <hip/hip_runtime.h>
#include <math.h>

#define HW 4096      // 64*64 feature locations
#define CC 256       // feature channels
#define C2 64        // value channels
#define E50f 1.928749848e-22f   // expf(-50)

typedef unsigned short USH;
typedef __attribute__((ext_vector_type(8))) _Float16 f16x8;
typedef __attribute__((ext_vector_type(8))) short bf8;
typedef __attribute__((ext_vector_type(4))) float f32x4;

__device__ __forceinline__ USH f2bf(float x) {
    unsigned u = __float_as_uint(x);
    u += 0x7fff + ((u >> 16) & 1);   // round-to-nearest-even
    return (USH)(u >> 16);
}
__device__ __forceinline__ USH f2h(float x) {
    _Float16 h = (_Float16)x;        // v_cvt_f16_f32, RTNE
    return *(USH*)&h;
}

// async global->LDS DMA, 16B per lane; LDS base must be wave-uniform
__device__ __forceinline__ void gl2lds16(const USH* g, USH* l) {
    __builtin_amdgcn_global_load_lds(
        (const __attribute__((address_space(1))) void*)g,
        (__attribute__((address_space(3))) void*)l, 16, 0, 0);
}

// ---------------------------------------------------------------------------
// D1: merged prep. blocks [0,512): per-channel means of fa/fb.
//     blocks [512,1536): bilinear 256->64 of unalign_fb fused with mask_b,
//     vtT build (chunked [qc][256m][32] bf16) and per-(pblock) bg partials.
// bgp layout: [pblk][320]: [0..255] rowsum[m] partials, [256..319] tot[c2].
__global__ void k_prep1(const float* __restrict__ fa, const float* __restrict__ fb,
                        float* __restrict__ mu,
                        const float* __restrict__ ufb_src, const int* __restrict__ fb_parse,
                        USH* __restrict__ vtT, float* __restrict__ bgp) {
    __shared__ float4 sred[256];
    int t = threadIdx.x;
    if (blockIdx.x < 512) {
        int b = blockIdx.x;
        const float* src = (b < CC) ? (fa + b * HW) : (fb + (b - CC) * HW);
        float s = 0.f;
        for (int q = t; q < HW; q += 256) s += src[q];
        sred[t].x = s;
        __syncthreads();
        for (int st = 128; st > 0; st >>= 1) {
            if (t < st) sred[t].x += sred[t + st].x;
            __syncthreads();
        }
        if (t == 0) mu[b] = sred[0].x * (1.0f / HW);
        return;
    }
    int bid = blockIdx.x - 512;
    int pblk = bid & 15, c = bid >> 4;
    int p = pblk * 256 + t;
    int j = p >> 6, i = p & 63;
    int off = (4 * j) * 256 + 4 * i;   // nearest: src = 4*dst
    float m0 = (fb_parse[1 * 65536 + off] != 0) ? 1.f : 0.f;
    float m1 = (fb_parse[2 * 65536 + off] != 0) ? 1.f : 0.f;
    float m2 = (fb_parse[3 * 65536 + off] != 0) ? 1.f : 0.f;
    float ry = j * (255.0f / 63.0f);
    int y0 = (int)ry; y0 = min(y0, 255); int y1 = min(y0 + 1, 255);
    float wy = ry - (float)y0;
    float rx = i * (255.0f / 63.0f);
    int x0 = (int)rx; x0 = min(x0, 255); int x1 = min(x0 + 1, 255);
    float wx = rx - (float)x0;
    const float* sc = ufb_src + c * 65536;
    float r0 = sc[y0 * 256 + x0] * (1.f - wx) + sc[y0 * 256 + x1] * wx;
    float r1 = sc[y1 * 256 + x0] * (1.f - wx) + sc[y1 * 256 + x1] * wx;
    float v = r0 * (1.f - wy) + r1 * wy;
    size_t cbase = (size_t)(p >> 5) * 8192 + (p & 31);
    vtT[cbase + (0 * 65 + c) * 32] = f2bf(v * m0);
    vtT[cbase + (1 * 65 + c) * 32] = f2bf(v * m1);
    vtT[cbase + (2 * 65 + c) * 32] = f2bf(v * m2);
    if (c == 0) {
        vtT[cbase + 64 * 32]  = f2bf(m0);
        vtT[cbase + 129 * 32] = f2bf(m1);
        vtT[cbase + 194 * 32] = f2bf(m2);
        for (int m = 195; m < 256; ++m) vtT[cbase + m * 32] = 0;
    }
    sred[t] = make_float4(v, v * m0, v * m1, v * m2);
    __syncthreads();
    for (int st = 128; st > 0; st >>= 1) {
        if (t < st) {
            float4 o = sred[t + st];
            sred[t].x += o.x; sred[t].y += o.y; sred[t].z += o.z; sred[t].w += o.w;
        }
        __syncthreads();
    }
    if (t == 0) {
        float4 r = sred[0];
        bgp[pblk * 320 + 256 + c]     = r.x;   // tot[c]
        bgp[pblk * 320 + 0 * 65 + c]  = r.y;   // rowsum value rows
        bgp[pblk * 320 + 1 * 65 + c]  = r.z;
        bgp[pblk * 320 + 2 * 65 + c]  = r.w;
    }
    __syncthreads();
    if (c == 0) {   // mask-row sums (block-uniform branch)
        sred[t] = make_float4(m0, m1, m2, 0.f);
        __syncthreads();
        for (int st = 128; st > 0; st >>= 1) {
            if (t < st) {
                float4 o = sred[t + st];
                sred[t].x += o.x; sred[t].y += o.y; sred[t].z += o.z;
            }
            __syncthreads();
        }
        if (t == 0) {
            float4 r = sred[0];
            bgp[pblk * 320 + 64]  = r.x;
            bgp[pblk * 320 + 129] = r.y;
            bgp[pblk * 320 + 194] = r.z;
        }
    }
}

// D2: fused center + L2-normalize + fp16 cast + chunked transpose.
// ssq summation order matches the original two-kernel path -> bit-identical.
__global__ __launch_bounds__(256) void k_normT(
    const float* __restrict__ fa, const float* __restrict__ fb,
    const float* __restrict__ mu_,
    USH* __restrict__ faT, USH* __restrict__ fbT) {
    __shared__ float tile[256][33];   // [c][p], +1 pad
    __shared__ float red[8][32];
    __shared__ float rv[32];
    int which = blockIdx.z;
    const float* src = which ? fb : fa;
    USH* dst = which ? fbT : faT;
    const float* mu = mu_ + which * CC;
    int p0 = blockIdx.x * 32;
    int t = threadIdx.x;
    int pi = t & 31, g = t >> 5;      // g in 0..7: 32-channel chunk
    for (int it = 0; it < 32; ++it) {
        int c = it * 8 + g;
        tile[c][pi] = src[(size_t)c * HW + p0 + pi];
    }
    __syncthreads();
    float ss = 0.f;
#pragma unroll
    for (int jc = 0; jc < 32; ++jc) {
        float v = tile[g * 32 + jc][pi] - mu[g * 32 + jc];
        ss += v * v;
    }
    red[g][pi] = ss;
    __syncthreads();
    if (g == 0) {
        float s2 = 0.f;
#pragma unroll
        for (int gg = 0; gg < 8; ++gg) s2 += red[gg][pi];
        rv[pi] = rsqrtf(s2);
    }
    __syncthreads();
    float rinv = rv[pi];
    size_t base = (size_t)g * 131072 + (size_t)(p0 + pi) * 32;
#pragma unroll
    for (int seg = 0; seg < 4; ++seg) {
        union { USH us[8]; uint4 v; } h;
#pragma unroll
        for (int jc = 0; jc < 8; ++jc)
            h.us[jc] = f2h((tile[g * 32 + seg * 8 + jc][pi] - mu[g * 32 + seg * 8 + jc]) * rinv);
        *(uint4*)&dst[base + seg * 8] = h.v;
    }
}

// D3: fused attention (v6, measured best). p-tile 128, 8 waves, 256 blocks
// (1/CU). XCD pinning z=bid&7; A staged once in LDS; B/V direct global->VGPR.
// Wave w: S-phase owns q rows 16w..16w+15; PV owns m rows 32w..32w+31.
__global__ __launch_bounds__(512, 2) void k_attn(
    const USH* __restrict__ faT, const USH* __restrict__ fbT,
    const USH* __restrict__ vtT, float* __restrict__ part) {
    __shared__ USH sA[8 * 4096];    // A tile [kc=8][128p][32c] fp16 (64 KB)
    __shared__ USH sE[128 * 136];   // E tile [128p][128q + pad] bf16 (34 KB)
    int t = threadIdx.x;
    int bid = blockIdx.x;
    int z = bid & 7;                // XCD = bid % 8 (round-robin)
    int p0 = (bid >> 3) * 128;
    int w = t >> 6, lane = t & 63, lr = lane & 15, quad = lane >> 4;
    f32x4 accp[2][8] = {};          // PV acc: m=32w+16i+4quad+r, p=p0+16jj+lr

    // prologue: stage the block's A-slice (128 rows x 256 ch) into LDS.
#pragma unroll
    for (int seg = 0; seg < 8; ++seg)
        gl2lds16(faT + (size_t)w * 131072 + (size_t)p0 * 32 + seg * 512 + lane * 8,
                 &sA[w * 4096 + seg * 512]);

    const USH* pB = fbT + (size_t)(z * 512 + 16 * w + lr) * 32 + quad * 8; // + kc*131072 + qt*4096
    const USH* pV = vtT + (size_t)(32 * w + lr) * 32 + quad * 8;           // + qc*8192 + i*512

    __syncthreads();               // A-stage complete (implies vmcnt drain)

    for (int qt = 0; qt < 4; ++qt) {
        f32x4 accs[8] = {};         // S acc: q=16w+4quad+r, p=16jj+lr
#pragma unroll
        for (int kc = 0; kc < 8; ++kc) {
            f16x8 a, b[8];
            a = *(const f16x8*)&pB[(size_t)kc * 131072 + qt * 4096];
#pragma unroll
            for (int jj = 0; jj < 8; ++jj)
                b[jj] = *(const f16x8*)&sA[kc * 4096 + (16 * jj + lr) * 32 + quad * 8];
#pragma unroll
            for (int jj = 0; jj < 8; ++jj)
                accs[jj] = __builtin_amdgcn_mfma_f32_16x16x32_f16(a, b[jj], accs[jj], 0, 0, 0);
        }
        // wait for previous qt's PV reads of sE before overwriting
        if (qt) __syncthreads();
        // exp -> bf16 -> transposed E tile in LDS: E[p][q]
#pragma unroll
        for (int jj = 0; jj < 8; ++jj) {
            unsigned u0 = ((unsigned)f2bf(__expf(fmaf(100.f, accs[jj][1], -50.f))) << 16)
                        | (unsigned)f2bf(__expf(fmaf(100.f, accs[jj][0], -50.f)));
            unsigned u1 = ((unsigned)f2bf(__expf(fmaf(100.f, accs[jj][3], -50.f))) << 16)
                        | (unsigned)f2bf(__expf(fmaf(100.f, accs[jj][2], -50.f)));
            int addr = (16 * jj + lr) * 136 + 16 * w + 4 * quad;
            uint2 u; u.x = u0; u.y = u1;
            *(uint2*)&sE[addr] = u;
        }
        __syncthreads();
        // PV: V from global (L2-hot), E from LDS.
        // pad rows m>=208: wave 7 all, wave 6 i==1 -> skip (wave-uniform).
#pragma unroll
        for (int kc = 0; kc < 4; ++kc) {
            size_t vb = (size_t)(z * 16 + qt * 4 + kc) * 8192;
            bf8 av[2] = {}, be[8];
#pragma unroll
            for (int i = 0; i < 2; ++i)
                if (!(w == 7 || (w == 6 && i == 1)))
                    av[i] = *(const bf8*)&pV[vb + i * 512];
#pragma unroll
            for (int jj = 0; jj < 8; ++jj)
                be[jj] = *(const bf8*)&sE[(16 * jj + lr) * 136 + kc * 32 + quad * 8];
#pragma unroll
            for (int i = 0; i < 2; ++i)
#pragma unroll
                for (int jj = 0; jj < 8; ++jj)
                    if (!(w == 7 || (w == 6 && i == 1)))
                        accp[i][jj] = __builtin_amdgcn_mfma_f32_16x16x32_bf16(av[i], be[jj], accp[i][jj], 0, 0, 0);
        }
    }
    // store only useful rows m < 195
    float* op = part + (size_t)z * 1048576;
#pragma unroll
    for (int i = 0; i < 2; ++i) {
        int m = 32 * w + 16 * i + 4 * quad;
#pragma unroll
        for (int jj = 0; jj < 8; ++jj) {
            int pc = p0 + 16 * jj + lr;
#pragma unroll
            for (int r = 0; r < 4; ++r)
                if (m + r < 195)
                    op[(size_t)(m + r) * HW + pc] = accp[i][jj][r];
        }
    }
}

// D4: 4 c2 per block (grid 16x16). den-row sums + mask_a once per block.
__global__ void k_combine8(const float* __restrict__ part, const float* __restrict__ bgp,
                           const int* __restrict__ fa_parse, float* __restrict__ aligned) {
    __shared__ float sden[3];
    __shared__ float sc2[4][4];    // [local c2][r: 0..2 rowsum_k, 3 tot]
    int t = threadIdx.x;
    int cg = blockIdx.y * 4;
    if (t < 19) {
        int idx;
        if (t < 3) idx = t * 65 + 64;
        else {
            int lc = (t - 3) >> 2, r = (t - 3) & 3;
            idx = (r < 3) ? r * 65 + (cg + lc) : 256 + (cg + lc);
        }
        float s = 0.f;
#pragma unroll
        for (int pb = 0; pb < 16; ++pb) s += bgp[pb * 320 + idx];
        if (t < 3) sden[t] = s;
        else sc2[(t - 3) >> 2][(t - 3) & 3] = s;
    }
    __syncthreads();
    int p = blockIdx.x * 256 + t;
    int jj = p >> 6, ii = p & 63;
    int off = (4 * jj) * 256 + 4 * ii;
    float ma[3], den[3];
    float s = 0.f;
#pragma unroll
    for (int k = 0; k < 3; ++k) {
        ma[k] = (fa_parse[(k + 1) * 65536 + off] != 0) ? 1.f : 0.f;
        s += ma[k];
        den[k] = E50f * (4096.0f - sden[k]);
        size_t rd = (size_t)(k * 65 + 64) * HW + p;
#pragma unroll
        for (int z = 0; z < 8; ++z) den[k] += part[(size_t)z * 1048576 + rd];
    }
    float fs = fmaxf(s, 1.f);
#pragma unroll
    for (int lc = 0; lc < 4; ++lc) {
        int c2 = cg + lc;
        float num = 0.f;
#pragma unroll
        for (int k = 0; k < 3; ++k) {
            float nu = E50f * (sc2[lc][3] - sc2[lc][k]);
            size_t rn = (size_t)(k * 65 + c2) * HW + p;
#pragma unroll
            for (int z = 0; z < 8; ++z) nu += part[(size_t)z * 1048576 + rn];
            num += ma[k] * (nu / den[k]);
        }
        aligned[(size_t)c2 * HW + p] = num / fs;
    }
}

// D5: bilinear align_corners 64->256, 4 outputs per thread
__global__ void k_bilin_up(const float* __restrict__ aligned, float* __restrict__ out) {
    int idx = (blockIdx.x * 256 + threadIdx.x) * 4;
    int c2 = blockIdx.y;
    int y = idx >> 8;
    float ry = y * (63.0f / 255.0f);
    int y0 = (int)ry; y0 = min(y0, 63); int y1 = min(y0 + 1, 63);
    float wy = ry - (float)y0;
    const float* a = aligned + c2 * HW;
    float4 o;
    float* op = &o.x;
#pragma unroll
    for (int u = 0; u < 4; ++u) {
        int x = (idx & 255) + u;
        float rx = x * (63.0f / 255.0f);
        int x0 = (int)rx; x0 = min(x0, 63); int x1 = min(x0 + 1, 63);
        float wx = rx - (float)x0;
        float r0 = a[y0 * 64 + x0] * (1.f - wx) + a[y0 * 64 + x1] * wx;
        float r1 = a[y1 * 64 + x0] * (1.f - wx) + a[y1 * 64 + x1] * wx;
        op[u] = r0 * (1.f - wy) + r1 * wy;
    }
    *(float4*)&out[c2 * 65536 + idx] = o;
}

extern "C" void kernel_launch(void* const* d_in, const int* in_sizes, int n_in,
                              void* d_out, int out_size, void* d_ws, size_t ws_size,
                              hipStream_t stream) {
    const float* unalign_fb = (const float*)d_in[0];   // (1,64,256,256)
    const float* fa         = (const float*)d_in[1];   // (1,256,64,64)
    const int*   fa_parse   = (const int*)d_in[2];     // (1,4,256,256)
    const float* fb         = (const float*)d_in[3];   // (1,256,64,64)
    const int*   fb_parse   = (const int*)d_in[4];     // (1,4,256,256)
    float* out = (float*)d_out;                         // (1,64,256,256)

    float* w = (float*)d_ws;
    float* mu       = w;                   // 512
    float* bgp      = w + 66048;           // 16*320 = 5120
    float* part     = w + 71168;           // 8*1048576
    float* aligned  = w + 8459776;         // 262144
    USH* faT = (USH*)(w + 8721920);        // [kc=8][4096p][32] fp16
    USH* fbT = (USH*)(w + 9246208);        // [kc=8][4096q][32] fp16
    USH* vtT = (USH*)(w + 9770496);        // [qc=128][256m][32] bf16

    k_prep1<<<dim3(1536), dim3(256), 0, stream>>>(fa, fb, mu, unalign_fb, fb_parse, vtT, bgp);
    k_normT<<<dim3(128, 1, 2), dim3(256), 0, stream>>>(fa, fb, mu, faT, fbT);
    k_attn<<<dim3(256), dim3(512), 0, stream>>>(faT, fbT, vtT, part);
    k_combine8<<<dim3(16, 16), dim3(256), 0, stream>>>(part, bgp, fa_parse, aligned);
    k_bilin_up<<<dim3(64, 64), dim3(256), 0, stream>>>(aligned, out);
}